// Round 4
// baseline (265.455 us; speedup 1.0000x reference)
//
#include <hip/hip_runtime.h>
#include <hip/hip_bf16.h>
#include <math.h>

#define NNODES 50000
#define NEDGES 800000
#define IN1 512
#define IN2 256
#define NOUT 128
#define FTOT 256   // combined feature width (two GCN branches)

typedef __attribute__((ext_vector_type(8))) short short8;
typedef __attribute__((ext_vector_type(4))) short short4v;
typedef __attribute__((ext_vector_type(8))) short frag_ab;
typedef __attribute__((ext_vector_type(4))) float frag_cd;

// ---------------- workspace layout (bytes) ----------------
#define OFF_XW      ((size_t)0)           // N*256 bf16 = 25,600,000
#define OFF_W1T     ((size_t)25600000)    // 128x512 bf16 [col][k]
#define OFF_W2T     ((size_t)25731072)    // 128x256 bf16 [col][k]
#define OFF_DEG     ((size_t)25796608)    // N int
#define OFF_DINV    ((size_t)25996672)    // N f32
#define OFF_ROWPTR  ((size_t)26196736)    // (N+1) int
#define OFF_CURSOR  ((size_t)26396800)    // N int
#define OFF_BSUM    ((size_t)26596864)    // 256 int
#define OFF_ADJ     ((size_t)26600960)    // E int

__device__ __forceinline__ short f2bf(float f) {
    union { float f; unsigned u; } x; x.f = f;
    unsigned r = x.u + 0x7fffu + ((x.u >> 16) & 1u);   // RNE
    return (short)(r >> 16);
}
__device__ __forceinline__ float bf2f(unsigned short u) {
    union { unsigned u; float f; } x; x.u = ((unsigned)u) << 16;
    return x.f;
}

// ---------------- small kernels ----------------

__global__ __launch_bounds__(256) void wcvt_kernel(const float* __restrict__ W1, const float* __restrict__ W2,
                                                   short* __restrict__ w1t, short* __restrict__ w2t) {
    int t = blockIdx.x * 256 + threadIdx.x;
    if (t < IN1 * NOUT) {
        int c = t & 127, k = t >> 7;
        w1t[c * IN1 + k] = f2bf(W1[t]);
    } else if (t < (IN1 + IN2) * NOUT) {
        int u = t - IN1 * NOUT;
        int c = u & 127, k = u >> 7;
        w2t[c * IN2 + k] = f2bf(W2[u]);
    }
}

__global__ __launch_bounds__(256) void hist_kernel(const int* __restrict__ ei, int* __restrict__ deg, int e) {
    int i = blockIdx.x * blockDim.x + threadIdx.x;
    if (i < e) atomicAdd(&deg[ei[e + i]], 1);
}

__global__ __launch_bounds__(256) void scan_part_kernel(const int* __restrict__ deg, float* __restrict__ dinv,
                                                        int* __restrict__ bsum, int n) {
    __shared__ int s[256];
    int t = threadIdx.x;
    int i = blockIdx.x * 256 + t;
    int v = (i < n) ? deg[i] : 0;
    if (i < n) dinv[i] = rsqrtf((float)(v + 1));
    s[t] = v; __syncthreads();
    #pragma unroll
    for (int off = 128; off > 0; off >>= 1) {
        if (t < off) s[t] += s[t + off];
        __syncthreads();
    }
    if (t == 0) bsum[blockIdx.x] = s[0];
}

__global__ __launch_bounds__(256) void scan_top_kernel(int* __restrict__ bsum, int nb) {
    __shared__ int s[256];
    int t = threadIdx.x;
    int v = (t < nb) ? bsum[t] : 0;
    s[t] = v; __syncthreads();
    for (int off = 1; off < 256; off <<= 1) {
        int u = (t >= off) ? s[t - off] : 0;
        __syncthreads();
        s[t] += u;
        __syncthreads();
    }
    if (t < nb) bsum[t] = s[t] - v;
}

__global__ __launch_bounds__(256) void scan_write_kernel(const int* __restrict__ deg, const int* __restrict__ bsum,
                                                         int* __restrict__ rowptr, int* __restrict__ cursor, int n) {
    __shared__ int s[256];
    int t = threadIdx.x;
    int i = blockIdx.x * 256 + t;
    int v = (i < n) ? deg[i] : 0;
    s[t] = v; __syncthreads();
    for (int off = 1; off < 256; off <<= 1) {
        int u = (t >= off) ? s[t - off] : 0;
        __syncthreads();
        s[t] += u;
        __syncthreads();
    }
    int base = bsum[blockIdx.x];
    if (i < n) { int rp = base + s[t] - v; rowptr[i] = rp; cursor[i] = rp; }
    if (i == n - 1) rowptr[n] = base + s[t];
}

__global__ __launch_bounds__(256) void fill_kernel(const int* __restrict__ ei,
                                                   int* __restrict__ cursor, int* __restrict__ adj, int e) {
    int i = blockIdx.x * blockDim.x + threadIdx.x;
    if (i < e) {
        int src = ei[i];
        int dst = ei[e + i];
        int pos = atomicAdd(&cursor[dst], 1);
        adj[pos] = src;
    }
}

// ---------------- barrier-free MFMA GEMM ----------------
// One wave owns a 16-row tile x all 128 output cols. A (16 rows x K) lives in
// registers as bf16 fragments; B fragments stream per-lane from L2 (W is
// 192 KB total, L2-resident). No LDS, no __syncthreads -- waves fully
// independent, latency hidden by ILP (8 B-loads + 8 A-loads in flight).
template<int K, int COLOFF>
__device__ __forceinline__ void gemm_tile(const float* __restrict__ X, const short* __restrict__ Wt,
                                          short* __restrict__ xw, int tile, int n) {
    constexpr int NSTEP = K / 32;
    const int lane = threadIdx.x & 63;
    const int l15 = lane & 15, kof = lane >> 4;
    const int r0 = tile * 16;
    int row = r0 + l15; if (row >= n) row = n - 1;
    const float* ap = X + (size_t)row * K + kof * 8;

    // ---- A: load f32, convert, keep bf16 fragments in registers ----
    frag_ab ab[NSTEP];
    #pragma unroll
    for (int g = 0; g < NSTEP; g += 4) {            // 4 steps per group: 8 loads in flight
        float4 f[8];
        #pragma unroll
        for (int s = 0; s < 4; ++s) {
            f[2*s]   = *reinterpret_cast<const float4*>(ap + (g + s) * 32);
            f[2*s+1] = *reinterpret_cast<const float4*>(ap + (g + s) * 32 + 4);
        }
        #pragma unroll
        for (int s = 0; s < 4; ++s) {
            frag_ab p;
            p[0]=f2bf(f[2*s].x);   p[1]=f2bf(f[2*s].y);   p[2]=f2bf(f[2*s].z);   p[3]=f2bf(f[2*s].w);
            p[4]=f2bf(f[2*s+1].x); p[5]=f2bf(f[2*s+1].y); p[6]=f2bf(f[2*s+1].z); p[7]=f2bf(f[2*s+1].w);
            ab[g + s] = p;
        }
    }

    // ---- MFMA: B fragment = 16B contiguous per lane, straight from global/L2 ----
    frag_cd acc[8];
    #pragma unroll
    for (int cf = 0; cf < 8; ++cf) acc[cf] = (frag_cd){0.f, 0.f, 0.f, 0.f};

    const short* bp = Wt + (size_t)l15 * K + kof * 8;
    #pragma unroll
    for (int step = 0; step < NSTEP; ++step) {
        #pragma unroll
        for (int cf = 0; cf < 8; ++cf) {
            frag_ab b = *reinterpret_cast<const frag_ab*>(bp + (size_t)cf * 16 * K + step * 32);
            acc[cf] = __builtin_amdgcn_mfma_f32_16x16x32_bf16(b, ab[step], acc[cf], 0, 0, 0);
        }
    }

    // ---- epilogue: lane holds out[row=r0+l15][cols kof*4..+3 of each 16-col frag] ----
    if (r0 + l15 < n) {
        short* dst = xw + (size_t)(r0 + l15) * FTOT + COLOFF + kof * 4;
        #pragma unroll
        for (int cf = 0; cf < 8; ++cf) {
            short4v pk;
            pk[0] = f2bf(acc[cf][0]); pk[1] = f2bf(acc[cf][1]);
            pk[2] = f2bf(acc[cf][2]); pk[3] = f2bf(acc[cf][3]);
            *reinterpret_cast<short4v*>(dst + cf * 16) = pk;
        }
    }
}

__global__ __launch_bounds__(256) void gemm_kernel(const float* __restrict__ x1, const float* __restrict__ x2,
                                                   const short* __restrict__ w1t, const short* __restrict__ w2t,
                                                   short* __restrict__ xw, int n, int t1, int t2) {
    int w = (int)((blockIdx.x * (size_t)blockDim.x + threadIdx.x) >> 6);
    if (w < t1)            gemm_tile<IN1, 0>(x1, w1t, xw, w, n);
    else if (w < t1 + t2)  gemm_tile<IN2, 128>(x2, w2t, xw, w - t1, n);
}

// ---------------- gather + epilogue ----------------
// one wave per node; lane owns 4 consecutive bf16 features; unroll-2 for MLP
__global__ __launch_bounds__(256) void gather_kernel(const unsigned short* __restrict__ xw,
                                                     const int* __restrict__ rowptr,
                                                     const int* __restrict__ adj,
                                                     const float* __restrict__ dinv,
                                                     const float* __restrict__ b1,
                                                     const float* __restrict__ b2,
                                                     float* __restrict__ out, int n) {
    int wid  = (int)((blockIdx.x * (size_t)blockDim.x + threadIdx.x) >> 6);
    int lane = threadIdx.x & 63;
    if (wid >= n) return;

    const ushort4* base = reinterpret_cast<const ushort4*>(xw);
    float ax = 0.f, ay = 0.f, az = 0.f, aw = 0.f;

    const int s = rowptr[wid], e = rowptr[wid + 1];
    int i = s;
    for (; i + 1 < e; i += 2) {                       // 2 independent row loads in flight
        int s0 = adj[i], s1 = adj[i + 1];
        float w0 = dinv[s0], w1 = dinv[s1];
        ushort4 v0 = base[(size_t)s0 * 64 + lane];
        ushort4 v1 = base[(size_t)s1 * 64 + lane];
        ax = fmaf(bf2f(v0.x), w0, ax); ay = fmaf(bf2f(v0.y), w0, ay);
        az = fmaf(bf2f(v0.z), w0, az); aw = fmaf(bf2f(v0.w), w0, aw);
        ax = fmaf(bf2f(v1.x), w1, ax); ay = fmaf(bf2f(v1.y), w1, ay);
        az = fmaf(bf2f(v1.z), w1, az); aw = fmaf(bf2f(v1.w), w1, aw);
    }
    if (i < e) {
        int s0 = adj[i];
        float w0 = dinv[s0];
        ushort4 v0 = base[(size_t)s0 * 64 + lane];
        ax = fmaf(bf2f(v0.x), w0, ax); ay = fmaf(bf2f(v0.y), w0, ay);
        az = fmaf(bf2f(v0.z), w0, az); aw = fmaf(bf2f(v0.w), w0, aw);
    }
    float di = dinv[wid];
    {   // self-loop
        ushort4 v = base[(size_t)wid * 64 + lane];
        ax = fmaf(bf2f(v.x), di, ax); ay = fmaf(bf2f(v.y), di, ay);
        az = fmaf(bf2f(v.z), di, az); aw = fmaf(bf2f(v.w), di, aw);
    }
    float4 bias = (lane < 32) ? reinterpret_cast<const float4*>(b1)[lane]
                              : reinterpret_cast<const float4*>(b2)[lane - 32];
    float4 v;
    v.x = fmaxf(fmaf(ax, di, bias.x), 0.f);
    v.y = fmaxf(fmaf(ay, di, bias.y), 0.f);
    v.z = fmaxf(fmaf(az, di, bias.z), 0.f);
    v.w = fmaxf(fmaf(aw, di, bias.w), 0.f);

    float4 h;
    h.x = v.x + __shfl_xor(v.x, 32);
    h.y = v.y + __shfl_xor(v.y, 32);
    h.z = v.z + __shfl_xor(v.z, 32);
    h.w = v.w + __shfl_xor(v.w, 32);

    float m = fmaxf(fmaxf(h.x, h.y), fmaxf(h.z, h.w));
    #pragma unroll
    for (int off = 1; off <= 16; off <<= 1) m = fmaxf(m, __shfl_xor(m, off));
    float ssum = __expf(h.x - m) + __expf(h.y - m) + __expf(h.z - m) + __expf(h.w - m);
    #pragma unroll
    for (int off = 1; off <= 16; off <<= 1) ssum += __shfl_xor(ssum, off);
    float lse = m + __logf(ssum);

    if (lane < 32) {
        float4 y;
        y.x = h.x - lse; y.y = h.y - lse; y.z = h.z - lse; y.w = h.w - lse;
        reinterpret_cast<float4*>(out)[(size_t)wid * 32 + lane] = y;
    }
}

// ---------------- launcher ----------------
extern "C" void kernel_launch(void* const* d_in, const int* in_sizes, int n_in,
                              void* d_out, int out_size, void* d_ws, size_t ws_size,
                              hipStream_t stream) {
    const float* x1 = (const float*)d_in[0];
    const float* x2 = (const float*)d_in[1];
    const int*   ei = (const int*)d_in[2];
    const float* W1 = (const float*)d_in[3];
    const float* b1 = (const float*)d_in[4];
    const float* W2 = (const float*)d_in[5];
    const float* b2 = (const float*)d_in[6];
    float* out = (float*)d_out;

    const int n = in_sizes[0] / IN1;       // 50000
    const int e = in_sizes[2] / 2;         // 800000

    char* ws = (char*)d_ws;
    short* xw     = (short*)(ws + OFF_XW);
    short* w1t    = (short*)(ws + OFF_W1T);
    short* w2t    = (short*)(ws + OFF_W2T);
    int*   deg    = (int*)  (ws + OFF_DEG);
    float* dinv   = (float*)(ws + OFF_DINV);
    int*   rowptr = (int*)  (ws + OFF_ROWPTR);
    int*   cursor = (int*)  (ws + OFF_CURSOR);
    int*   bsum   = (int*)  (ws + OFF_BSUM);
    int*   adj    = (int*)  (ws + OFF_ADJ);

    const int nb_n = (n + 255) / 256;      // 196
    const int nb_e = (e + 255) / 256;

    hipMemsetAsync(deg, 0, (size_t)n * sizeof(int), stream);

    wcvt_kernel<<<((IN1 + IN2) * NOUT + 255) / 256, 256, 0, stream>>>(W1, W2, w1t, w2t);
    hist_kernel<<<nb_e, 256, 0, stream>>>(ei, deg, e);
    scan_part_kernel<<<nb_n, 256, 0, stream>>>(deg, dinv, bsum, n);
    scan_top_kernel<<<1, 256, 0, stream>>>(bsum, nb_n);
    scan_write_kernel<<<nb_n, 256, 0, stream>>>(deg, bsum, rowptr, cursor, n);
    fill_kernel<<<nb_e, 256, 0, stream>>>(ei, cursor, adj, e);

    const int t1 = (n + 15) / 16;          // 3125 wave-tiles, modality 1
    const int t2 = (n + 15) / 16;          // 3125 wave-tiles, modality 2
    const int waves = t1 + t2;
    const int gblocks = (waves + 3) / 4;   // 4 waves per 256-thread block
    gemm_kernel<<<gblocks, 256, 0, stream>>>(x1, x2, w1t, w2t, xw, n, t1, t2);

    const int waves_per_block = 4;
    int gb = (n + waves_per_block - 1) / waves_per_block;
    gather_kernel<<<gb, 256, 0, stream>>>((const unsigned short*)xw, rowptr, adj, dinv, b1, b2, out, n);
}

// Round 5
// 198.120 us; speedup vs baseline: 1.3399x; 1.3399x over previous
//
#include <hip/hip_runtime.h>
#include <hip/hip_bf16.h>
#include <math.h>

#define NNODES 50000
#define NEDGES 800000
#define IN1 512
#define IN2 256
#define NOUT 128
#define FTOT 256   // combined feature width (two GCN branches)

typedef __attribute__((ext_vector_type(4))) short short4v;
typedef __attribute__((ext_vector_type(8))) short frag_ab;
typedef __attribute__((ext_vector_type(4))) float frag_cd;

// ---------------- workspace layout (bytes) ----------------
#define OFF_XW      ((size_t)0)           // N*256 bf16 = 25,600,000 (pre-scaled by dinv[row])
#define OFF_W1T     ((size_t)25600000)    // 128x512 bf16 [col][k]
#define OFF_W2T     ((size_t)25731072)    // 128x256 bf16 [col][k]
#define OFF_DEG     ((size_t)25796608)    // N int
#define OFF_DINV    ((size_t)25996672)    // N f32
#define OFF_ROWPTR  ((size_t)26196736)    // (N+1) int
#define OFF_CURSOR  ((size_t)26396800)    // N int
#define OFF_BSUM    ((size_t)26596864)    // 256 int
#define OFF_ADJ     ((size_t)26600960)    // E int

__device__ __forceinline__ short f2bf(float f) {
    union { float f; unsigned u; } x; x.f = f;
    unsigned r = x.u + 0x7fffu + ((x.u >> 16) & 1u);   // RNE
    return (short)(r >> 16);
}
__device__ __forceinline__ float bf2f(unsigned short u) {
    union { unsigned u; float f; } x; x.u = ((unsigned)u) << 16;
    return x.f;
}

// ---------------- small kernels ----------------

__global__ __launch_bounds__(256) void wcvt_kernel(const float* __restrict__ W1, const float* __restrict__ W2,
                                                   short* __restrict__ w1t, short* __restrict__ w2t) {
    int t = blockIdx.x * 256 + threadIdx.x;
    if (t < IN1 * NOUT) {
        int c = t & 127, k = t >> 7;
        w1t[c * IN1 + k] = f2bf(W1[t]);
    } else if (t < (IN1 + IN2) * NOUT) {
        int u = t - IN1 * NOUT;
        int c = u & 127, k = u >> 7;
        w2t[c * IN2 + k] = f2bf(W2[u]);
    }
}

__global__ __launch_bounds__(256) void hist_kernel(const int* __restrict__ ei, int* __restrict__ deg, int e) {
    int i = blockIdx.x * blockDim.x + threadIdx.x;
    if (i < e) atomicAdd(&deg[ei[e + i]], 1);
}

__global__ __launch_bounds__(256) void scan_part_kernel(const int* __restrict__ deg, float* __restrict__ dinv,
                                                        int* __restrict__ bsum, int n) {
    __shared__ int s[256];
    int t = threadIdx.x;
    int i = blockIdx.x * 256 + t;
    int v = (i < n) ? deg[i] : 0;
    if (i < n) dinv[i] = rsqrtf((float)(v + 1));
    s[t] = v; __syncthreads();
    #pragma unroll
    for (int off = 128; off > 0; off >>= 1) {
        if (t < off) s[t] += s[t + off];
        __syncthreads();
    }
    if (t == 0) bsum[blockIdx.x] = s[0];
}

__global__ __launch_bounds__(256) void scan_top_kernel(int* __restrict__ bsum, int nb) {
    __shared__ int s[256];
    int t = threadIdx.x;
    int v = (t < nb) ? bsum[t] : 0;
    s[t] = v; __syncthreads();
    for (int off = 1; off < 256; off <<= 1) {
        int u = (t >= off) ? s[t - off] : 0;
        __syncthreads();
        s[t] += u;
        __syncthreads();
    }
    if (t < nb) bsum[t] = s[t] - v;
}

__global__ __launch_bounds__(256) void scan_write_kernel(const int* __restrict__ deg, const int* __restrict__ bsum,
                                                         int* __restrict__ rowptr, int* __restrict__ cursor, int n) {
    __shared__ int s[256];
    int t = threadIdx.x;
    int i = blockIdx.x * 256 + t;
    int v = (i < n) ? deg[i] : 0;
    s[t] = v; __syncthreads();
    for (int off = 1; off < 256; off <<= 1) {
        int u = (t >= off) ? s[t - off] : 0;
        __syncthreads();
        s[t] += u;
        __syncthreads();
    }
    int base = bsum[blockIdx.x];
    if (i < n) { int rp = base + s[t] - v; rowptr[i] = rp; cursor[i] = rp; }
    if (i == n - 1) rowptr[n] = base + s[t];
}

__global__ __launch_bounds__(256) void fill_kernel(const int* __restrict__ ei,
                                                   int* __restrict__ cursor, int* __restrict__ adj, int e) {
    int i = blockIdx.x * blockDim.x + threadIdx.x;
    if (i < e) {
        int src = ei[i];
        int dst = ei[e + i];
        int pos = atomicAdd(&cursor[dst], 1);
        adj[pos] = src;
    }
}

// ---------------- MFMA GEMM: reg-staged 2-phase, barrier-cost-free ----------------
// BM=128, BN=128, BK=64, 4 waves (2x2, each 64x64). Both A and B are staged
// global->reg->LDS so NO global_load_lds exists: every vmem load is consumed
// before __syncthreads, hence the barrier's implicit vmcnt(0) drain is free and
// the step-top prefetch has a full BW-limited step (~3.3k cy) to land.
// LDS layout [k8][slot=row^k8][8] (XOR swizzle): frag reads conflict-free,
// stage writes <=4-way.
#define GBM 128
#define GBK 64

template<int K, int COLOFF>
__device__ __forceinline__ void gemm_tile(const float* __restrict__ X, const short* __restrict__ Wt,
                                          const float* __restrict__ dinv, short* __restrict__ xw,
                                          short (*As)[8][128][8], short (*Bs)[8][128][8],
                                          int tileIdx, int n) {
    constexpr int NT = K / GBK;
    const int t    = threadIdx.x;
    const int lane = t & 63;
    const int wave = t >> 6;
    const int wr   = wave >> 1, wc = wave & 1;
    const int l15  = lane & 15, kof = lane >> 4;
    const int rowBase = tileIdx * GBM;

    // A staging: thread covers rows a_r+16i (i=0..7), k-quad a_kq..a_kq+3
    const int a_r  = t >> 4;
    const int a_kq = (t & 15) * 4;
    const int a_k8 = a_kq >> 3;
    const int a_j  = a_kq & 7;        // 0 or 4
    // B staging: thread covers cols b_c0+32i (i=0..3), k-chunk b_k8 (8 elems)
    const int b_k8 = t & 7;
    const int b_c0 = t >> 3;

    float4  an[8];
    frag_ab bn[4];

    auto issueLoads = [&](int kt) {
        #pragma unroll
        for (int i = 0; i < 8; ++i) {
            int g = rowBase + a_r + i * 16; if (g >= n) g = n - 1;
            an[i] = *reinterpret_cast<const float4*>(X + (size_t)g * K + kt + a_kq);
        }
        #pragma unroll
        for (int i = 0; i < 4; ++i)
            bn[i] = *reinterpret_cast<const frag_ab*>(Wt + (size_t)(b_c0 + i * 32) * K + kt + b_k8 * 8);
    };
    auto writeStage = [&](int buf) {
        #pragma unroll
        for (int i = 0; i < 8; ++i) {
            int r = a_r + i * 16;
            short4v p;
            p[0] = f2bf(an[i].x); p[1] = f2bf(an[i].y);
            p[2] = f2bf(an[i].z); p[3] = f2bf(an[i].w);
            *reinterpret_cast<short4v*>(&As[buf][a_k8][r ^ a_k8][a_j]) = p;
        }
        #pragma unroll
        for (int i = 0; i < 4; ++i)
            *reinterpret_cast<frag_ab*>(&Bs[buf][b_k8][(b_c0 + i * 32) ^ b_k8][0]) = bn[i];
    };

    frag_cd acc[4][4];
    #pragma unroll
    for (int i = 0; i < 4; ++i)
        #pragma unroll
        for (int j = 0; j < 4; ++j)
            acc[i][j] = (frag_cd){0.f, 0.f, 0.f, 0.f};

    // prologue: stage tile 0
    issueLoads(0);
    writeStage(0);
    __syncthreads();

    int cur = 0;
    for (int it = 0; it < NT; ++it) {
        if (it + 1 < NT) issueLoads((it + 1) * GBK);   // prefetch: consumed after MFMA

        frag_ab afr[2][4], bfr[2][4];
        #pragma unroll
        for (int ks = 0; ks < 2; ++ks) {
            const int k8a = ks * 4 + kof;
            #pragma unroll
            for (int mf = 0; mf < 4; ++mf)
                afr[ks][mf] = *reinterpret_cast<const frag_ab*>(&As[cur][k8a][(wr * 64 + mf * 16 + l15) ^ k8a][0]);
            #pragma unroll
            for (int nf = 0; nf < 4; ++nf)
                bfr[ks][nf] = *reinterpret_cast<const frag_ab*>(&Bs[cur][k8a][(wc * 64 + nf * 16 + l15) ^ k8a][0]);
        }

        __builtin_amdgcn_s_setprio(1);
        #pragma unroll
        for (int ks = 0; ks < 2; ++ks)
            #pragma unroll
            for (int mf = 0; mf < 4; ++mf)
                #pragma unroll
                for (int nf = 0; nf < 4; ++nf)
                    acc[mf][nf] = __builtin_amdgcn_mfma_f32_16x16x32_bf16(bfr[ks][nf], afr[ks][mf], acc[mf][nf], 0, 0, 0);
        __builtin_amdgcn_s_setprio(0);

        if (it + 1 < NT) writeStage(cur ^ 1);   // consume prefetch -> vmcnt 0 at barrier
        __syncthreads();
        cur ^= 1;
    }

    // epilogue: lane holds out[row = l15-based][cols kof*4..+3 of each frag];
    // pre-scale by dinv[row] so the gather needs no per-edge weight.
    #pragma unroll
    for (int mf = 0; mf < 4; ++mf) {
        int orow = rowBase + wr * 64 + mf * 16 + l15;
        if (orow < n) {
            float di = dinv[orow];
            short* dst = xw + (size_t)orow * FTOT + COLOFF + wc * 64 + kof * 4;
            #pragma unroll
            for (int nf = 0; nf < 4; ++nf) {
                short4v pk;
                pk[0] = f2bf(acc[mf][nf][0] * di); pk[1] = f2bf(acc[mf][nf][1] * di);
                pk[2] = f2bf(acc[mf][nf][2] * di); pk[3] = f2bf(acc[mf][nf][3] * di);
                *reinterpret_cast<short4v*>(dst + nf * 16) = pk;
            }
        }
    }
}

__global__ __launch_bounds__(256, 2) void gemm_kernel(const float* __restrict__ x1, const float* __restrict__ x2,
                                                      const short* __restrict__ w1t, const short* __restrict__ w2t,
                                                      const float* __restrict__ dinv, short* __restrict__ xw,
                                                      int n, int t1b) {
    __shared__ short As[2][8][128][8];   // 32 KiB
    __shared__ short Bs[2][8][128][8];   // 32 KiB
    int b = blockIdx.x;
    if (b < t1b) gemm_tile<IN1, 0>(x1, w1t, dinv, xw, As, Bs, b, n);
    else         gemm_tile<IN2, 128>(x2, w2t, dinv, xw, As, Bs, b - t1b, n);
}

// ---------------- gather + epilogue ----------------
// one wave per node; xw rows are pre-scaled by dinv[src] -> plain sum.
__global__ __launch_bounds__(256) void gather_kernel(const unsigned short* __restrict__ xw,
                                                     const int* __restrict__ rowptr,
                                                     const int* __restrict__ adj,
                                                     const float* __restrict__ dinv,
                                                     const float* __restrict__ b1,
                                                     const float* __restrict__ b2,
                                                     float* __restrict__ out, int n) {
    int wid  = (int)((blockIdx.x * (size_t)blockDim.x + threadIdx.x) >> 6);
    int lane = threadIdx.x & 63;
    if (wid >= n) return;

    const ushort4* base = reinterpret_cast<const ushort4*>(xw);
    float ax = 0.f, ay = 0.f, az = 0.f, aw = 0.f;

    const int s = rowptr[wid], e = rowptr[wid + 1];
    int i = s;
    for (; i + 3 < e; i += 4) {                       // 4 independent row loads in flight
        int s0 = adj[i], s1 = adj[i + 1], s2 = adj[i + 2], s3 = adj[i + 3];
        ushort4 v0 = base[(size_t)s0 * 64 + lane];
        ushort4 v1 = base[(size_t)s1 * 64 + lane];
        ushort4 v2 = base[(size_t)s2 * 64 + lane];
        ushort4 v3 = base[(size_t)s3 * 64 + lane];
        ax += bf2f(v0.x) + bf2f(v1.x) + bf2f(v2.x) + bf2f(v3.x);
        ay += bf2f(v0.y) + bf2f(v1.y) + bf2f(v2.y) + bf2f(v3.y);
        az += bf2f(v0.z) + bf2f(v1.z) + bf2f(v2.z) + bf2f(v3.z);
        aw += bf2f(v0.w) + bf2f(v1.w) + bf2f(v2.w) + bf2f(v3.w);
    }
    for (; i < e; ++i) {
        int s0 = adj[i];
        ushort4 v0 = base[(size_t)s0 * 64 + lane];
        ax += bf2f(v0.x); ay += bf2f(v0.y); az += bf2f(v0.z); aw += bf2f(v0.w);
    }
    {   // self-loop (xw already has dinv[node] folded in)
        ushort4 v = base[(size_t)wid * 64 + lane];
        ax += bf2f(v.x); ay += bf2f(v.y); az += bf2f(v.z); aw += bf2f(v.w);
    }
    float di = dinv[wid];
    float4 bias = (lane < 32) ? reinterpret_cast<const float4*>(b1)[lane]
                              : reinterpret_cast<const float4*>(b2)[lane - 32];
    float4 v;
    v.x = fmaxf(fmaf(ax, di, bias.x), 0.f);
    v.y = fmaxf(fmaf(ay, di, bias.y), 0.f);
    v.z = fmaxf(fmaf(az, di, bias.z), 0.f);
    v.w = fmaxf(fmaf(aw, di, bias.w), 0.f);

    float4 h;
    h.x = v.x + __shfl_xor(v.x, 32);
    h.y = v.y + __shfl_xor(v.y, 32);
    h.z = v.z + __shfl_xor(v.z, 32);
    h.w = v.w + __shfl_xor(v.w, 32);

    float m = fmaxf(fmaxf(h.x, h.y), fmaxf(h.z, h.w));
    #pragma unroll
    for (int off = 1; off <= 16; off <<= 1) m = fmaxf(m, __shfl_xor(m, off));
    float ssum = __expf(h.x - m) + __expf(h.y - m) + __expf(h.z - m) + __expf(h.w - m);
    #pragma unroll
    for (int off = 1; off <= 16; off <<= 1) ssum += __shfl_xor(ssum, off);
    float lse = m + __logf(ssum);

    if (lane < 32) {
        float4 y;
        y.x = h.x - lse; y.y = h.y - lse; y.z = h.z - lse; y.w = h.w - lse;
        reinterpret_cast<float4*>(out)[(size_t)wid * 32 + lane] = y;
    }
}

// ---------------- launcher ----------------
extern "C" void kernel_launch(void* const* d_in, const int* in_sizes, int n_in,
                              void* d_out, int out_size, void* d_ws, size_t ws_size,
                              hipStream_t stream) {
    const float* x1 = (const float*)d_in[0];
    const float* x2 = (const float*)d_in[1];
    const int*   ei = (const int*)d_in[2];
    const float* W1 = (const float*)d_in[3];
    const float* b1 = (const float*)d_in[4];
    const float* W2 = (const float*)d_in[5];
    const float* b2 = (const float*)d_in[6];
    float* out = (float*)d_out;

    const int n = in_sizes[0] / IN1;       // 50000
    const int e = in_sizes[2] / 2;         // 800000

    char* ws = (char*)d_ws;
    short* xw     = (short*)(ws + OFF_XW);
    short* w1t    = (short*)(ws + OFF_W1T);
    short* w2t    = (short*)(ws + OFF_W2T);
    int*   deg    = (int*)  (ws + OFF_DEG);
    float* dinv   = (float*)(ws + OFF_DINV);
    int*   rowptr = (int*)  (ws + OFF_ROWPTR);
    int*   cursor = (int*)  (ws + OFF_CURSOR);
    int*   bsum   = (int*)  (ws + OFF_BSUM);
    int*   adj    = (int*)  (ws + OFF_ADJ);

    const int nb_n = (n + 255) / 256;      // 196
    const int nb_e = (e + 255) / 256;

    hipMemsetAsync(deg, 0, (size_t)n * sizeof(int), stream);

    wcvt_kernel<<<((IN1 + IN2) * NOUT + 255) / 256, 256, 0, stream>>>(W1, W2, w1t, w2t);
    hist_kernel<<<nb_e, 256, 0, stream>>>(ei, deg, e);
    scan_part_kernel<<<nb_n, 256, 0, stream>>>(deg, dinv, bsum, n);
    scan_top_kernel<<<1, 256, 0, stream>>>(bsum, nb_n);
    scan_write_kernel<<<nb_n, 256, 0, stream>>>(deg, bsum, rowptr, cursor, n);
    fill_kernel<<<nb_e, 256, 0, stream>>>(ei, cursor, adj, e);

    const int t1b = (n + GBM - 1) / GBM;   // 391 (mod1, K=512, launched first: LPT)
    const int t2b = (n + GBM - 1) / GBM;   // 391 (mod2, K=256)
    gemm_kernel<<<t1b + t2b, 256, 0, stream>>>(x1, x2, w1t, w2t, dinv, xw, n, t1b);

    const int waves_per_block = 4;
    int gb = (n + waves_per_block - 1) / waves_per_block;
    gather_kernel<<<gb, 256, 0, stream>>>((const unsigned short*)xw, rowptr, adj, dinv, b1, b2, out, n);
}